// Round 1
// baseline (1305.734 us; speedup 1.0000x reference)
//
#include <hip/hip_runtime.h>
#include <stdint.h>

// ---------------------------------------------------------------------------
// GraphAggregator: fused 3-layer MLP (256->512->512->128) + SiLU + segment-sum
// V2: BM=64 (halves per-row weight L2 traffic, the measured bottleneck),
//     transposed MFMA (weights as A-operand) -> vectorized epilogue stores,
//     kt-major weight packing (imm-offset fragment loads), cvt_pk bf16 pack.
// ---------------------------------------------------------------------------

typedef short bf16x8 __attribute__((ext_vector_type(8)));   // 8 bf16 = 4 VGPRs
typedef float f32x4  __attribute__((ext_vector_type(4)));

#define N_NODES   500000
#define BM        64
#define N_BLOCKS  ((N_NODES + BM - 1) / BM)   // 7813, last block has 32 rows
#define N_GRAPHS  1024
#define N_OUT     128

// packed-weight offsets in bf16 elements inside d_ws (917504 B total)
#define W1P_ELEMS (256*512)           // 131072
#define W2P_ELEMS (512*512)           // 262144
#define W3P_ELEMS (512*128)           // 65536
#define W2P_OFF   (W1P_ELEMS)
#define W3P_OFF   (W1P_ELEMS + W2P_ELEMS)
#define PREPACK_THREADS ((W1P_ELEMS + W2P_ELEMS + W3P_ELEMS) / 8)  // 57344

__device__ __forceinline__ short f2bf(float x) {
    // round-to-nearest-even fp32 -> bf16 (inputs are finite)
    uint32_t u = __float_as_uint(x);
    u += 0x7fffu + ((u >> 16) & 1u);
    return (short)(u >> 16);
}

// pack two fp32 -> one u32 holding 2 bf16 (RTNE), single HW instruction
__device__ __forceinline__ uint32_t pk2(float lo, float hi) {
    uint32_t r;
    asm("v_cvt_pk_bf16_f32 %0, %1, %2" : "=v"(r) : "v"(lo), "v"(hi));
    return r;
}

// Pack W[K][N] (row-major fp32) into MFMA fragments, kt-major:
// frag f = kt*NT + nt ;  dst[(f*64 + lane)*8 + j] =
//   bf16( W[kt*32 + (lane>>4)*8 + j][nt*16 + (lane&15)] )
// Used as the *A* operand of mfma(Wfrag, Actfrag, acc): A[i=n][k] = W[k][n].
__global__ void prepack_weights(const float* __restrict__ W1,
                                const float* __restrict__ W2,
                                const float* __restrict__ W3,
                                short* __restrict__ wp) {
    int tid = blockIdx.x * blockDim.x + threadIdx.x;
    if (tid >= PREPACK_THREADS) return;
    const float* src; int N, ntmask, ntshift, dstoff, local;
    if (tid < 16384) {              // W1: K=256 (8 kt), N=512 (32 nt)
        src = W1; N = 512; ntmask = 31; ntshift = 5; dstoff = 0;       local = tid;
    } else if (tid < 49152) {       // W2: K=512 (16 kt), N=512 (32 nt)
        src = W2; N = 512; ntmask = 31; ntshift = 5; dstoff = W2P_OFF; local = tid - 16384;
    } else {                        // W3: K=512 (16 kt), N=128 (8 nt)
        src = W3; N = 128; ntmask = 7;  ntshift = 3; dstoff = W3P_OFF; local = tid - 49152;
    }
    const int lane = local & 63;
    const int f  = local >> 6;
    const int nt = f & ntmask;
    const int kt = f >> ntshift;
    const int k0 = kt * 32 + (lane >> 4) * 8;
    const int n  = nt * 16 + (lane & 15);
    const float* s = src + (size_t)k0 * N + n;
    union { bf16x8 v; short e[8]; } u;
#pragma unroll
    for (int j = 0; j < 8; ++j) u.e[j] = f2bf(s[(size_t)j * N]);
    *((bf16x8*)(wp + dstoff) + local) = u.v;
}

// ---------------------------------------------------------------------------
// Fused kernel. 512 threads (8 waves), 1 block/CU. LDS map (128 KiB):
//   R0 [0,64K):   X tile bf16 (64 x 256, 512 B/row, swizzled)  -> h2 (64 x 512)
//   R1 [64K,128K): h1 bf16 (64 x 512, 1024 B/row, swizzled)    -> y f32 (64 x 132)
// Swizzle: 16B granule g stored at g ^ (row & 7) -> conflict-free b128 reads.
// MFMA is called transposed: mfma(Wfrag, ActFrag, acc) -> D[n][m] with
//   lane: m = lane&15 (fixed), n = ntile*16 + (lane>>4)*4 + r  (4 consecutive
//   columns per lane) -> epilogue = 2x cvt_pk + one 8-B LDS store.
// ---------------------------------------------------------------------------
__launch_bounds__(512, 2)
__global__ void fused_mlp(const float* __restrict__ X,
                          const int*   __restrict__ gidx,
                          const short* __restrict__ wp,
                          const float* __restrict__ b1,
                          const float* __restrict__ b2,
                          const float* __restrict__ b3,
                          float* __restrict__ out) {
    __shared__ __align__(16) char lds[131072];
    char* R0 = lds;
    char* R1 = lds + 65536;

    const int t    = threadIdx.x;
    const int lane = t & 63;
    const int wave = t >> 6;          // 0..7
    const int q    = lane >> 4;       // quad 0..3
    const int l15  = lane & 15;
    const int64_t rowBase = (int64_t)blockIdx.x * BM;
    int rowsValid = N_NODES - (int)rowBase;
    if (rowsValid > BM) rowsValid = BM;

    const f32x4 zero4 = {0.f, 0.f, 0.f, 0.f};

    // ---------------- Phase 0: stage X (64 x 256 fp32 -> bf16, swizzled) ----
    {
        const int m  = t >> 3;        // 0..63 row
        const int s  = t & 7;         // col slot
        const int sw = m & 7;
        const bool valid = ((int)rowBase + m) < N_NODES;
        const float* xr = X + (rowBase + m) * 256;
#pragma unroll
        for (int i = 0; i < 8; ++i) {
            const int col = (s + 8 * i) * 4;           // 4-float chunk
            uint2 w; w.x = 0u; w.y = 0u;
            if (valid) {
                const float4 f = *(const float4*)(xr + col);
                w.x = pk2(f.x, f.y);
                w.y = pk2(f.z, f.w);
            }
            const int c = col >> 3;                    // 16B granule
            const int off = m * 512 + ((c ^ sw) << 4) + ((col >> 2) & 1) * 8;
            *(uint2*)(R0 + off) = w;
        }
    }
    __syncthreads();

    // ---------------- Phase 1: h1 = relu(X @ W1 + b1)   K=256 -> R1 --------
    {
        f32x4 acc[4][4];
#pragma unroll
        for (int rt = 0; rt < 4; ++rt)
#pragma unroll
            for (int c = 0; c < 4; ++c) acc[rt][c] = zero4;
        const bf16x8* wB = (const bf16x8*)wp;          // W1 packed, kt-major
#pragma unroll 2
        for (int kt = 0; kt < 8; ++kt) {
            bf16x8 a[4];
#pragma unroll
            for (int rt = 0; rt < 4; ++rt) {
                const int m = rt * 16 + l15;
                a[rt] = *(const bf16x8*)(R0 + m * 512 + (((kt * 4 + q) ^ (m & 7)) << 4));
            }
            const bf16x8* bp = wB + ((kt * 32 + wave * 4) * 64 + lane);
#pragma unroll
            for (int c = 0; c < 4; ++c) {
                const bf16x8 b = bp[c * 64];           // imm offsets 0/1K/2K/3K
#pragma unroll
                for (int rt = 0; rt < 4; ++rt)
                    acc[rt][c] = __builtin_amdgcn_mfma_f32_16x16x32_bf16(b, a[rt], acc[rt][c], 0, 0, 0);
            }
        }
#pragma unroll
        for (int c = 0; c < 4; ++c) {
            const int n0 = (wave * 4 + c) * 16 + q * 4;
            const float4 bb = *(const float4*)(b1 + n0);
            const int cg = n0 >> 3;
            const int hb = (n0 & 7) << 1;              // 0 or 8
#pragma unroll
            for (int rt = 0; rt < 4; ++rt) {
                const int m = rt * 16 + l15;
                const float v0 = fmaxf(acc[rt][c][0] + bb.x, 0.f);
                const float v1 = fmaxf(acc[rt][c][1] + bb.y, 0.f);
                const float v2 = fmaxf(acc[rt][c][2] + bb.z, 0.f);
                const float v3 = fmaxf(acc[rt][c][3] + bb.w, 0.f);
                uint2 w; w.x = pk2(v0, v1); w.y = pk2(v2, v3);
                *(uint2*)(R1 + m * 1024 + ((cg ^ (m & 7)) << 4) + hb) = w;
            }
        }
    }
    __syncthreads();

    // ---------------- Phase 2: h2 = relu(h1 @ W2 + b2)  K=512 -> R0 --------
    {
        f32x4 acc[4][4];
#pragma unroll
        for (int rt = 0; rt < 4; ++rt)
#pragma unroll
            for (int c = 0; c < 4; ++c) acc[rt][c] = zero4;
        const bf16x8* wB = (const bf16x8*)wp + (W2P_OFF >> 3);
#pragma unroll 2
        for (int kt = 0; kt < 16; ++kt) {
            bf16x8 a[4];
#pragma unroll
            for (int rt = 0; rt < 4; ++rt) {
                const int m = rt * 16 + l15;
                a[rt] = *(const bf16x8*)(R1 + m * 1024 + (((kt * 4 + q) ^ (m & 7)) << 4));
            }
            const bf16x8* bp = wB + ((kt * 32 + wave * 4) * 64 + lane);
#pragma unroll
            for (int c = 0; c < 4; ++c) {
                const bf16x8 b = bp[c * 64];
#pragma unroll
                for (int rt = 0; rt < 4; ++rt)
                    acc[rt][c] = __builtin_amdgcn_mfma_f32_16x16x32_bf16(b, a[rt], acc[rt][c], 0, 0, 0);
            }
        }
#pragma unroll
        for (int c = 0; c < 4; ++c) {
            const int n0 = (wave * 4 + c) * 16 + q * 4;
            const float4 bb = *(const float4*)(b2 + n0);
            const int cg = n0 >> 3;
            const int hb = (n0 & 7) << 1;
#pragma unroll
            for (int rt = 0; rt < 4; ++rt) {
                const int m = rt * 16 + l15;
                const float v0 = fmaxf(acc[rt][c][0] + bb.x, 0.f);
                const float v1 = fmaxf(acc[rt][c][1] + bb.y, 0.f);
                const float v2 = fmaxf(acc[rt][c][2] + bb.z, 0.f);
                const float v3 = fmaxf(acc[rt][c][3] + bb.w, 0.f);
                uint2 w; w.x = pk2(v0, v1); w.y = pk2(v2, v3);
                *(uint2*)(R0 + m * 1024 + ((cg ^ (m & 7)) << 4) + hb) = w;
            }
        }
    }
    __syncthreads();

    // ---------------- Phase 3: y = silu(h2 @ W3 + b3)   K=512 -> R1 (f32) --
    {
        f32x4 acc[4];
#pragma unroll
        for (int rt = 0; rt < 4; ++rt) acc[rt] = zero4;
        const bf16x8* wB = (const bf16x8*)wp + (W3P_OFF >> 3);
        for (int kt = 0; kt < 16; ++kt) {
            bf16x8 a[4];
#pragma unroll
            for (int rt = 0; rt < 4; ++rt) {
                const int m = rt * 16 + l15;
                a[rt] = *(const bf16x8*)(R0 + m * 1024 + (((kt * 4 + q) ^ (m & 7)) << 4));
            }
            const bf16x8 b = wB[(kt * 8 + wave) * 64 + lane];
#pragma unroll
            for (int rt = 0; rt < 4; ++rt)
                acc[rt] = __builtin_amdgcn_mfma_f32_16x16x32_bf16(b, a[rt], acc[rt], 0, 0, 0);
        }
        float* yl = (float*)R1;                        // 64 x 132 f32 (pad +4)
        const int n0 = wave * 16 + q * 4;
        const float4 bb = *(const float4*)(b3 + n0);
#pragma unroll
        for (int rt = 0; rt < 4; ++rt) {
            const int m = rt * 16 + l15;
            const float y0 = acc[rt][0] + bb.x;
            const float y1 = acc[rt][1] + bb.y;
            const float y2 = acc[rt][2] + bb.z;
            const float y3 = acc[rt][3] + bb.w;
            float4 o;
            o.x = y0 / (1.f + __expf(-y0));
            o.y = y1 / (1.f + __expf(-y1));
            o.z = y2 / (1.f + __expf(-y2));
            o.w = y3 / (1.f + __expf(-y3));
            *(float4*)(yl + m * 132 + n0) = o;
        }
    }
    __syncthreads();

    // ---------------- Phase 4: segmented reduction + global atomics --------
    {
        int* gs = (int*)R0;                             // h2 dead, reuse
        if (t < BM) {
            const int r = (int)rowBase + t;
            gs[t] = (r < N_NODES) ? gidx[r] : 0;
        }
        __syncthreads();
        const int col = t & 127;
        const int r0  = (t >> 7) * 16;                  // four 16-row groups
        int rend = r0 + 16;
        if (rend > rowsValid) rend = rowsValid;
        if (r0 < rend) {
            const float* yl = (const float*)R1;
            int   gprev = gs[r0];
            float acc   = 0.f;
            for (int r = r0; r < rend; ++r) {
                const int gr = gs[r];
                if (gr != gprev) {
                    atomicAdd(out + gprev * N_OUT + col, acc);
                    acc = 0.f;
                    gprev = gr;
                }
                acc += yl[r * 132 + col];
            }
            atomicAdd(out + gprev * N_OUT + col, acc);
        }
    }
}

extern "C" void kernel_launch(void* const* d_in, const int* in_sizes, int n_in,
                              void* d_out, int out_size, void* d_ws, size_t ws_size,
                              hipStream_t stream) {
    const float* X    = (const float*)d_in[0];
    const int*   gidx = (const int*)  d_in[1];
    const float* W1   = (const float*)d_in[2];
    const float* b1   = (const float*)d_in[3];
    const float* W2   = (const float*)d_in[4];
    const float* b2   = (const float*)d_in[5];
    const float* W3   = (const float*)d_in[6];
    const float* b3   = (const float*)d_in[7];
    float* out = (float*)d_out;
    short* wp  = (short*)d_ws;      // packed bf16 weights, 917504 bytes

    // out is poisoned 0xAA before every timed launch -> zero it (atomic target)
    hipMemsetAsync(d_out, 0, sizeof(float) * N_GRAPHS * N_OUT, stream);

    prepack_weights<<<PREPACK_THREADS / 256, 256, 0, stream>>>(W1, W2, W3, wp);

    fused_mlp<<<N_BLOCKS, 512, 0, stream>>>(X, gidx, wp, b1, b2, b3, out);
}